// Round 13
// baseline (2208.889 us; speedup 1.0000x reference)
//
#include <hip/hip_runtime.h>
#include <math.h>

typedef short bf16x8 __attribute__((ext_vector_type(8)));
typedef short bf16x4 __attribute__((ext_vector_type(4)));
typedef float f32x4  __attribute__((ext_vector_type(4)));

#define TT 32
#define MM 16
#define CC 128
#define NPT 32768
#define NC 4194304          // NPT*CC, elements per time-slice
#define BN 16               // n-points per tile
#define NTILE 8             // tiles per persistent block (grid = 256)

// ---- LDS layout (bytes), total 163840 = 160 KiB exactly ----
// XF : bf16 [m16][n16][i128][ri2] = 131072 B, phys = L ^ ((n&7)<<4)
// OF0/OF1 : bf16 [no256][k2_32], row stride 64 B, byte-in-row b -> b ^ ((no&7)<<3)
// rfft tables (f32[512] x2 = 4 KB) OVERLAY OF1[0:4096] (dead during DFT phase)
#define XF_OFF   0
#define OF0_OFF  131072
#define OF1_OFF  147456
#define LDS_BYTES 163840

static __device__ __forceinline__ unsigned short f2bf(float f) {
    union { float f; unsigned u; } v; v.f = f;
    unsigned r = v.u + 0x7FFFu + ((v.u >> 16) & 1u);   // RNE
    return (unsigned short)(r >> 16);
}
static __device__ __forceinline__ unsigned pack2(float lo, float hi) {
    return (unsigned)f2bf(lo) | ((unsigned)f2bf(hi) << 16);
}
static __device__ __forceinline__ float uplo(unsigned u) {
    return __uint_as_float(u << 16);
}
static __device__ __forceinline__ float uphi(unsigned u) {
    return __uint_as_float(u & 0xFFFF0000u);
}

// ============================================================================
// Weight repack: w[i][o][m][ri] f32 -> bf16 MFMA B-fragments in d_ws.
// Layout (short8 rows): WB[m][og][riOut][ck][lane] — per (m,og) contiguous 16 KB.
// Row holds B[k = ck*32 + (lane>>4)*8 + j][o = og*16 + (lane&15)], j=0..7,
// k = 2i+ri_in stacking:  B_R = {+Wr, -Wi},  B_I = {+Wi, +Wr}.
// ============================================================================
__global__ void repack_w(const float* __restrict__ w, bf16x8* __restrict__ wb) {
    int r = blockIdx.x * blockDim.x + threadIdx.x;    // 0..131071
    int lane = r & 63;
    int r2 = r >> 6;
    int ck = r2 & 7;
    int r3 = r2 >> 3;
    int ri = r3 & 1;
    int r4 = r3 >> 1;
    int og = r4 & 7;
    int m  = r4 >> 3;
    int o = og * 16 + (lane & 15);
    int kbase = ck * 32 + (lane >> 4) * 8;
    bf16x8 v;
    #pragma unroll
    for (int j = 0; j < 8; ++j) {
        int k = kbase + j;
        int i = k >> 1, ko = k & 1;
        const float* wp = w + ((size_t)(i * 128 + o) * 16 + m) * 2;
        float val;
        if (ri == 0) val = ko ? -wp[1] : wp[0];
        else         val = ko ?  wp[0] : wp[1];
        v[j] = (short)f2bf(val);
    }
    wb[r] = v;
}

// DFT pass over one col-pair sourced from a px register array (static idx).
// Writes XF bytes [ib*4+BOFF, +8) of each (m,nn) row.
#define DFT_PASS(PX, BOFF)                                                    \
  {                                                                           \
    _Pragma("unroll")                                                         \
    for (int half = 0; half < 2; ++half) {                                    \
      const int mh = half * 8;                                                \
      float xr0[8], xi0[8], xr1[8], xi1[8];                                   \
      {                                                                       \
        float a0 = uplo(PX[0]),  a1 = uphi(PX[0]);                            \
        float b0 = uplo(PX[16]), b1 = uphi(PX[16]);                           \
        _Pragma("unroll")                                                     \
        for (int m = 0; m < 8; ++m) {                                         \
          float sgn = ((mh + m) & 1) ? -1.f : 1.f;                            \
          xr0[m] = a0 + sgn * b0;  xr1[m] = a1 + sgn * b1;                    \
          xi0[m] = 0.f;            xi1[m] = 0.f;                              \
        }                                                                     \
      }                                                                       \
      _Pragma("unroll")                                                       \
      for (int t = 1; t <= 15; ++t) {                                         \
        unsigned u = PX[t], v = PX[32 - t];                                   \
        float e0 = uplo(u) + uplo(v), o0 = uplo(u) - uplo(v);                 \
        float e1 = uphi(u) + uphi(v), o1 = uphi(u) - uphi(v);                 \
        float4 cA = *(const float4*)&tabc[t * 16 + mh];                       \
        float4 cB = *(const float4*)&tabc[t * 16 + mh + 4];                   \
        float4 sA = *(const float4*)&tabs[t * 16 + mh];                       \
        float4 sB = *(const float4*)&tabs[t * 16 + mh + 4];                   \
        float cm[8] = {cA.x,cA.y,cA.z,cA.w, cB.x,cB.y,cB.z,cB.w};             \
        float sm[8] = {sA.x,sA.y,sA.z,sA.w, sB.x,sB.y,sB.z,sB.w};             \
        _Pragma("unroll")                                                     \
        for (int m = 0; m < 8; ++m) {                                         \
          xr0[m] += e0 * cm[m];  xi0[m] -= o0 * sm[m];                        \
          xr1[m] += e1 * cm[m];  xi1[m] -= o1 * sm[m];                        \
        }                                                                     \
      }                                                                       \
      _Pragma("unroll")                                                       \
      for (int m = 0; m < 8; ++m) {                                           \
        unsigned byte = ((unsigned)((mh + m) * 8192 + nn * 512 + ib * 4 + (BOFF))) ^ swzd; \
        uint2 v2;                                                             \
        v2.x = pack2(xr0[m], xi0[m]);                                         \
        v2.y = pack2(xr1[m], xi1[m]);                                         \
        *(uint2*)(xfb + byte) = v2;                                           \
      }                                                                       \
    }                                                                         \
  }

// ============================================================================
// Persistent fused kernel: 256 blocks x 512 threads (8 waves), 1 block/CU.
// BN=16, NTILE=8. Each wave: einsum modes {wid, wid+8}, irfft n {wid, wid+8}.
// All x sourced from px registers (packed bf16, 64 VGPR), refilled for tile
// j+1 with coalesced float4 loads spread across tile j's og pipeline.
// ============================================================================
__global__ __launch_bounds__(512, 1)
void spectral_mfma(const float* __restrict__ x, const bf16x8* __restrict__ wb,
                   float* __restrict__ out) {
    extern __shared__ char lds[];
    float* tabc = (float*)(lds + OF1_OFF);          // overlays OF1[0:2048]
    float* tabs = (float*)(lds + OF1_OFF + 2048);   // overlays OF1[2048:4096]
    const int tid = threadIdx.x;

    // DFT mapping: thread = (n-row, 4 i-cols)
    const int nn = tid >> 5;            // 0..15
    const int ib = (tid & 31) * 4;      // i-base
    const unsigned swzd = (unsigned)((nn & 7) << 4);

    // einsum/irfft mapping
    const int lane = tid & 63;
    const int wid  = tid >> 6;          // 0..7
    const int col  = lane & 15;
    const int kq   = lane >> 4;
    const unsigned swza = (unsigned)((col & 7) << 4);
    const unsigned swzo = (unsigned)((col & 7) << 3);

    // per-thread irfft fragments DT[t=col | col+16][k2 = kq*8 + jj]  (16 VGPR)
    bf16x8 dtf0, dtf1;
    #pragma unroll
    for (int jm = 0; jm < 4; ++jm) {
        int m = kq * 4 + jm;
        float alpha = (m == 0) ? 0.03125f : 0.0625f;   // 1/32, 2/32
        float s, c;
        sincosf(0.19634954084936207f * (float)((m * col) & 31), &s, &c);
        dtf0[jm * 2 + 0] = (short)f2bf(alpha * c);
        dtf0[jm * 2 + 1] = (m == 0) ? (short)0 : (short)f2bf(-alpha * s);
        sincosf(0.19634954084936207f * (float)((m * (col + 16)) & 31), &s, &c);
        dtf1[jm * 2 + 0] = (short)f2bf(alpha * c);
        dtf1[jm * 2 + 1] = (m == 0) ? (short)0 : (short)f2bf(-alpha * s);
    }

    char* xfb = lds + XF_OFF;
    const size_t xcolbase = (size_t)(blockIdx.x * NTILE * BN + nn) * CC + ib;

    // ---------- prologue: load+pack x for tile 0 (4 cols, 64 VGPR) ----------
    unsigned pxA[32], pxB[32];
    #pragma unroll
    for (int t = 0; t < 32; ++t) {
        float4 a = *(const float4*)(x + xcolbase + (size_t)t * NC);
        pxA[t] = pack2(a.x, a.y);
        pxB[t] = pack2(a.z, a.w);
    }

    for (int jt = 0; jt < NTILE; ++jt) {
        const int n0 = (blockIdx.x * NTILE + jt) * BN;

        // ---------- rfft tables [t][m] (overlay OF1; rewritten per tile) -----
        {
            int m = tid & 15, t = tid >> 4;
            float s, c;
            sincosf(0.19634954084936207f * (float)((m * t) & 31), &s, &c);
            tabc[t * 16 + m] = c;
            tabs[t * 16 + m] = s;
        }
        __syncthreads();

        // ---------- DFT from px regs -> XF (2 col-pairs x 2 m-halves) --------
        DFT_PASS(pxA, 0)
        DFT_PASS(pxB, 8)
        __syncthreads();

        // ---------- og pipeline (UNROLLED): einsum(k) || irfft(k-1) ----------
        const float* xnext = x + xcolbase + (size_t)((jt + 1) * BN) * CC;
        const bool havenext = (jt + 1 < NTILE);
        f32x4 sv0[2], sv1[2];
        #pragma unroll
        for (int rr = 0; rr < 2; ++rr) {
            sv0[rr] = (f32x4){0.f,0.f,0.f,0.f};
            sv1[rr] = (f32x4){0.f,0.f,0.f,0.f};
        }

        #pragma unroll
        for (int k = 0; k <= 8; ++k) {
            if (k < 8) {
                // einsum: modes wid and wid+8, o-tile k, K=256 over (i,ri)
                char* ofb = lds + ((k & 1) ? OF1_OFF : OF0_OFF);
                #pragma unroll
                for (int mm = 0; mm < 2; ++mm) {
                    const int m = wid + mm * 8;
                    const unsigned arow = (unsigned)(m * 8192 + col * 512 + kq * 16);
                    const bf16x8* wog = wb + (size_t)((m * 8 + k) * 2) * (8 * 64);
                    f32x4 accR = {0.f, 0.f, 0.f, 0.f};
                    f32x4 accI = {0.f, 0.f, 0.f, 0.f};
                    #pragma unroll
                    for (int ck = 0; ck < 8; ++ck) {
                        bf16x8 af = *(const bf16x8*)(xfb + ((arow + (unsigned)(ck * 64)) ^ swza));
                        bf16x8 bR = wog[(0 * 8 + ck) * 64 + lane];
                        bf16x8 bI = wog[(1 * 8 + ck) * 64 + lane];
                        accR = __builtin_amdgcn_mfma_f32_16x16x32_bf16(af, bR, accR, 0, 0, 0);
                        accI = __builtin_amdgcn_mfma_f32_16x16x32_bf16(af, bI, accI, 0, 0, 0);
                    }
                    #pragma unroll
                    for (int j = 0; j < 4; ++j) {
                        unsigned no = (unsigned)((kq * 4 + j) * 16 + col);
                        unsigned addr = no * 64u + (((unsigned)(m * 4)) ^ ((no & 7) << 3));
                        *(unsigned*)(ofb + addr) = pack2(accR[j], accI[j]);
                    }
                }
            }
            if (k > 0) {
                // irfft of o-tile (k-1); n-rows wid and wid+8
                const int og = k - 1;
                char* ofb = lds + ((og & 1) ? OF1_OFF : OF0_OFF);
                #pragma unroll
                for (int rr = 0; rr < 2; ++rr) {
                    const int r = wid + rr * 8;
                    unsigned rowb = (unsigned)((r * 16 + col) * 64);
                    bf16x4 lo = *(const bf16x4*)(ofb + rowb + (((unsigned)(kq * 16)) ^ swzo));
                    bf16x4 hi = *(const bf16x4*)(ofb + rowb + (((unsigned)(kq * 16 + 8)) ^ swzo));
                    bf16x8 pf;
                    #pragma unroll
                    for (int q = 0; q < 4; ++q) { pf[q] = lo[q]; pf[4 + q] = hi[q]; }
                    f32x4 z = {0.f, 0.f, 0.f, 0.f};
                    f32x4 c0 = __builtin_amdgcn_mfma_f32_16x16x32_bf16(dtf0, pf, z, 0, 0, 0);
                    f32x4 c1 = __builtin_amdgcn_mfma_f32_16x16x32_bf16(dtf1, pf, z, 0, 0, 0);
                    if ((og & 1) == 0) {
                        sv0[rr] = c0; sv1[rr] = c1;   // buffer even og
                    } else {
                        float* outp = out + (size_t)(n0 + r) * CC + col;
                        float* opE = outp + (og - 1) * 16;
                        float* opO = outp + og * 16;
                        #pragma unroll
                        for (int j = 0; j < 4; ++j) {
                            int t0 = kq * 4 + j;
                            opE[(size_t)t0 * NC]        = sv0[rr][j];  // adjacent
                            opO[(size_t)t0 * NC]        = c0[j];       // 64B halves
                            opE[(size_t)(t0 + 16) * NC] = sv1[rr][j];
                            opO[(size_t)(t0 + 16) * NC] = c1[j];
                        }
                    }
                }
            }
            // px refill for next tile: 4 t-slices per og step, coalesced float4
            if (k < 8) {
                if (havenext) {
                    #pragma unroll
                    for (int q = 0; q < 4; ++q) {
                        const int t = k * 4 + q;                 // static (k unrolled)
                        float4 a = *(const float4*)(xnext + (size_t)t * NC);
                        pxA[t] = pack2(a.x, a.y);
                        pxB[t] = pack2(a.z, a.w);
                    }
                }
            }
            __syncthreads();
        }
    }
}

// ============================================================================
// Fallback (round-1 proven kernel) — used only if ws_size < 2 MB.
// ============================================================================
#define FBN 8
#define FXST 36
__global__ __launch_bounds__(512, 2)
void spectral_fused(const float* __restrict__ x,
                    const float* __restrict__ w,
                    float* __restrict__ out) {
    extern __shared__ float flds[];
    float* xf    = flds;
    float* ftabc = flds + FBN * CC * FXST;
    float* ftabs = ftabc + 512;

    const int tid = threadIdx.x;
    const int n0  = blockIdx.x * FBN;

    {
        const int m = tid >> 5;
        const int t = tid & 31;
        const float ang = 0.19634954084936207f * (float)((m * t) & 31);
        float s, c; sincosf(ang, &s, &c);
        ftabc[tid] = c; ftabs[tid] = s;
    }
    __syncthreads();
    {
        const int i   = tid & 127;
        const int nnA = tid >> 7;
        const int nnB = nnA + 4;
        float xra[MM], xia[MM], xrb[MM], xib[MM];
        #pragma unroll
        for (int m = 0; m < MM; ++m) { xra[m]=0.f; xia[m]=0.f; xrb[m]=0.f; xib[m]=0.f; }
        const float* xA = x + (size_t)(n0 + nnA) * CC + i;
        const float* xB = x + (size_t)(n0 + nnB) * CC + i;
        for (int t = 0; t < TT; ++t) {
            const float va = xA[(size_t)t * NC];
            const float vb = xB[(size_t)t * NC];
            #pragma unroll
            for (int m = 0; m < MM; ++m) {
                const float c = ftabc[(m << 5) + t];
                const float s = ftabs[(m << 5) + t];
                xra[m] += va * c;  xia[m] -= va * s;
                xrb[m] += vb * c;  xib[m] -= vb * s;
            }
        }
        float* dA = xf + (size_t)(nnA * CC + i) * FXST;
        float* dB = xf + (size_t)(nnB * CC + i) * FXST;
        #pragma unroll
        for (int j = 0; j < 8; ++j) {
            *(float4*)(dA + 4 * j) = make_float4(xra[2*j], xia[2*j], xra[2*j+1], xia[2*j+1]);
            *(float4*)(dB + 4 * j) = make_float4(xrb[2*j], xib[2*j], xrb[2*j+1], xib[2*j+1]);
        }
    }
    __syncthreads();
    const int o   = tid & 127;
    const int nnA = tid >> 7;
    const int nnB = nnA + 4;
    float ar[MM], ai_[MM], br[MM], bi_[MM];
    #pragma unroll
    for (int m = 0; m < MM; ++m) { ar[m]=0.f; ai_[m]=0.f; br[m]=0.f; bi_[m]=0.f; }
    const float* qa0 = xf + (size_t)(nnA * CC) * FXST;
    const float* qb0 = xf + (size_t)(nnB * CC) * FXST;
    float4 wv[8];
    {
        const float4* wp = (const float4*)(w + (size_t)o * 32);
        #pragma unroll
        for (int j = 0; j < 8; ++j) wv[j] = wp[j];
    }
    for (int i = 0; i < CC; ++i) {
        float4 xa4[8], xb4[8];
        const float4* qa = (const float4*)(qa0 + i * FXST);
        const float4* qb = (const float4*)(qb0 + i * FXST);
        #pragma unroll
        for (int j = 0; j < 8; ++j) { xa4[j] = qa[j]; xb4[j] = qb[j]; }
        float4 wn[8];
        if (i + 1 < CC) {
            const float4* wp = (const float4*)(w + (size_t)((i + 1) * CC + o) * 32);
            #pragma unroll
            for (int j = 0; j < 8; ++j) wn[j] = wp[j];
        }
        #pragma unroll
        for (int j = 0; j < 8; ++j) {
            const int m0 = 2 * j, m1 = 2 * j + 1;
            ar[m0]  += xa4[j].x * wv[j].x - xa4[j].y * wv[j].y;
            ai_[m0] += xa4[j].x * wv[j].y + xa4[j].y * wv[j].x;
            br[m0]  += xb4[j].x * wv[j].x - xb4[j].y * wv[j].y;
            bi_[m0] += xb4[j].x * wv[j].y + xb4[j].y * wv[j].x;
            ar[m1]  += xa4[j].z * wv[j].z - xa4[j].w * wv[j].w;
            ai_[m1] += xa4[j].z * wv[j].w + xa4[j].w * wv[j].z;
            br[m1]  += xb4[j].z * wv[j].z - xb4[j].w * wv[j].w;
            bi_[m1] += xb4[j].z * wv[j].w + xb4[j].w * wv[j].z;
        }
        #pragma unroll
        for (int j = 0; j < 8; ++j) wv[j] = wn[j];
    }
    {
        const float inv = 1.0f / 32.0f;
        const size_t obA = (size_t)(n0 + nnA) * CC + o;
        const size_t obB = (size_t)(n0 + nnB) * CC + o;
        for (int t = 0; t < TT; ++t) {
            float accA = 0.f, accB = 0.f;
            #pragma unroll
            for (int m = 1; m < MM; ++m) {
                const float c = ftabc[(m << 5) + t];
                const float s = ftabs[(m << 5) + t];
                accA += ar[m] * c - ai_[m] * s;
                accB += br[m] * c - bi_[m] * s;
            }
            out[(size_t)t * NC + obA] = (ar[0] + 2.f * accA) * inv;
            out[(size_t)t * NC + obB] = (br[0] + 2.f * accB) * inv;
        }
    }
}

extern "C" void kernel_launch(void* const* d_in, const int* in_sizes, int n_in,
                              void* d_out, int out_size, void* d_ws, size_t ws_size,
                              hipStream_t stream) {
    (void)in_sizes; (void)n_in; (void)out_size;
    const float* x = (const float*)d_in[0];
    const float* w = (const float*)d_in[1];
    float* out     = (float*)d_out;

    if (d_ws != nullptr && ws_size >= (size_t)2 * 1024 * 1024) {
        bf16x8* wbuf = (bf16x8*)d_ws;
        hipLaunchKernelGGL(repack_w, dim3(512), dim3(256), 0, stream, w, wbuf);
        hipLaunchKernelGGL(spectral_mfma, dim3(256), dim3(512), LDS_BYTES, stream,
                           x, wbuf, out);
    } else {
        const size_t lds_bytes = (size_t)(FBN * CC * FXST + 1024) * sizeof(float);
        hipLaunchKernelGGL(spectral_fused, dim3(NPT / FBN), dim3(512), lds_bytes, stream,
                           x, w, out);
    }
}

// Round 15
// 438.409 us; speedup vs baseline: 5.0384x; 5.0384x over previous
//
#include <hip/hip_runtime.h>
#include <math.h>

typedef short bf16x8 __attribute__((ext_vector_type(8)));
typedef short bf16x4 __attribute__((ext_vector_type(4)));
typedef float f32x4  __attribute__((ext_vector_type(4)));
typedef float f32x2  __attribute__((ext_vector_type(2)));   // clang-native for NT builtins

#define TT 32
#define MM 16
#define CC 128
#define NPT 32768
#define NC 4194304          // NPT*CC, elements per time-slice
#define BN 16               // n-points per block

// ---- LDS layout (bytes), total 163840 = 160 KiB exactly ----
// XF : bf16 [m16][n16][i128][ri2] = 131072 B, phys = L ^ ((n&7)<<4)
// OF0/OF1 : bf16 [no256][k2_32], row stride 64 B, byte-in-row b -> b ^ ((no&7)<<3)
// rfft tables (f32[512] x2 = 4 KB) OVERLAY OF1[0:4096] (dead until og k=1)
#define XF_OFF   0
#define OF0_OFF  131072
#define OF1_OFF  147456
#define LDS_BYTES 163840

static __device__ __forceinline__ unsigned short f2bf(float f) {
    union { float f; unsigned u; } v; v.f = f;
    unsigned r = v.u + 0x7FFFu + ((v.u >> 16) & 1u);   // RNE
    return (unsigned short)(r >> 16);
}
static __device__ __forceinline__ unsigned pack2(float lo, float hi) {
    return (unsigned)f2bf(lo) | ((unsigned)f2bf(hi) << 16);
}

// ============================================================================
// Weight repack: w[i][o][m][ri] f32 -> bf16 MFMA B-fragments in d_ws.
// Layout (short8 rows): WB[m][og][riOut][ck][lane] — per (m,og) contiguous 16 KB.
// Row holds B[k = ck*32 + (lane>>4)*8 + j][o = og*16 + (lane&15)], j=0..7,
// k = 2i+ri_in stacking:  B_R = {+Wr, -Wi},  B_I = {+Wi, +Wr}.
// ============================================================================
__global__ void repack_w(const float* __restrict__ w, bf16x8* __restrict__ wb) {
    int r = blockIdx.x * blockDim.x + threadIdx.x;    // 0..131071
    int lane = r & 63;
    int r2 = r >> 6;
    int ck = r2 & 7;
    int r3 = r2 >> 3;
    int ri = r3 & 1;
    int r4 = r3 >> 1;
    int og = r4 & 7;
    int m  = r4 >> 3;
    int o = og * 16 + (lane & 15);
    int kbase = ck * 32 + (lane >> 4) * 8;
    bf16x8 v;
    #pragma unroll
    for (int j = 0; j < 8; ++j) {
        int k = kbase + j;
        int i = k >> 1, ko = k & 1;
        const float* wp = w + ((size_t)(i * 128 + o) * 16 + m) * 2;
        float val;
        if (ri == 0) val = ko ? -wp[1] : wp[0];
        else         val = ko ?  wp[0] : wp[1];
        v[j] = (short)f2bf(val);
    }
    wb[r] = v;
}

// ============================================================================
// Main fused kernel: 2048 blocks x 1024 threads (16 waves), BN=16.
// R12 structure + nontemporal x loads / out stores (x and out have zero reuse;
// keep them out of L2/L3 so the 2 MB weight set stays resident) + dtf derived
// from LDS tables (kills 16 serial sincosf per thread).
// ============================================================================
__global__ __launch_bounds__(1024, 2)
void spectral_mfma(const float* __restrict__ x, const bf16x8* __restrict__ wb,
                   float* __restrict__ out) {
    extern __shared__ char lds[];
    float* tabc = (float*)(lds + OF1_OFF);          // overlays OF1[0:2048]
    float* tabs = (float*)(lds + OF1_OFF + 2048);   // overlays OF1[2048:4096]
    const int tid = threadIdx.x;
    const int n0  = blockIdx.x * BN;

    // einsum/irfft mapping
    const int lane = tid & 63;
    const int wid  = tid >> 6;          // einsum: mode; irfft: n-row
    const int col  = lane & 15;
    const int kq   = lane >> 4;
    const unsigned swza = (unsigned)((col & 7) << 4);   // XF read swizzle
    const unsigned swzo = (unsigned)((col & 7) << 3);   // OF swizzle (no&7==col&7)

    // ---------- phase 0: rfft tables [t][m] (overlay OF1) ----------
    if (tid < 512) {
        int m = tid & 15, t = tid >> 4;
        float s, c;
        sincosf(0.19634954084936207f * (float)((m * t) & 31), &s, &c);
        tabc[t * 16 + m] = c;
        tabs[t * 16 + m] = s;
    }
    __syncthreads();

    // per-thread irfft fragments DT[t=col | col+16][k2 = kq*8 + jj] from tables
    bf16x8 dtf0, dtf1;
    #pragma unroll
    for (int jm = 0; jm < 4; ++jm) {
        int m = kq * 4 + jm;
        float alpha = (m == 0) ? 0.03125f : 0.0625f;   // 1/32, 2/32
        dtf0[jm * 2 + 0] = (short)f2bf(alpha * tabc[col * 16 + m]);
        dtf0[jm * 2 + 1] = (m == 0) ? (short)0
                                    : (short)f2bf(-alpha * tabs[col * 16 + m]);
        dtf1[jm * 2 + 0] = (short)f2bf(alpha * tabc[(col + 16) * 16 + m]);
        dtf1[jm * 2 + 1] = (m == 0) ? (short)0
                                    : (short)f2bf(-alpha * tabs[(col + 16) * 16 + m]);
    }

    // ---------- phase 1: folded rfft, two adjacent i-columns per thread ----------
    {
        const int nn = tid >> 6;            // 0..15
        const int i2 = (tid & 63) * 2;
        const float* xp = x + (size_t)(n0 + nn) * CC + i2;
        f32x2 x0  = __builtin_nontemporal_load((const f32x2*)(xp));
        f32x2 x16 = __builtin_nontemporal_load((const f32x2*)(xp + (size_t)16 * NC));
        float xrA[16], xiA[16], xrB[16], xiB[16];
        #pragma unroll
        for (int m = 0; m < 16; ++m) {
            float sgn = (m & 1) ? -1.f : 1.f;
            xrA[m] = x0[0] + sgn * x16[0];
            xrB[m] = x0[1] + sgn * x16[1];
            xiA[m] = 0.f; xiB[m] = 0.f;
        }
        #pragma unroll 3
        for (int t = 1; t <= 15; ++t) {
            f32x2 a = __builtin_nontemporal_load((const f32x2*)(xp + (size_t)t * NC));
            f32x2 b = __builtin_nontemporal_load((const f32x2*)(xp + (size_t)(32 - t) * NC));
            float ex = a[0] + b[0], ey = a[1] + b[1];
            float ox = a[0] - b[0], oy = a[1] - b[1];
            float4 c0 = *(const float4*)&tabc[t * 16 + 0];
            float4 c1 = *(const float4*)&tabc[t * 16 + 4];
            float4 c2 = *(const float4*)&tabc[t * 16 + 8];
            float4 c3 = *(const float4*)&tabc[t * 16 + 12];
            float4 s0 = *(const float4*)&tabs[t * 16 + 0];
            float4 s1 = *(const float4*)&tabs[t * 16 + 4];
            float4 s2 = *(const float4*)&tabs[t * 16 + 8];
            float4 s3 = *(const float4*)&tabs[t * 16 + 12];
            float cm[16] = {c0.x,c0.y,c0.z,c0.w, c1.x,c1.y,c1.z,c1.w,
                            c2.x,c2.y,c2.z,c2.w, c3.x,c3.y,c3.z,c3.w};
            float sm[16] = {s0.x,s0.y,s0.z,s0.w, s1.x,s1.y,s1.z,s1.w,
                            s2.x,s2.y,s2.z,s2.w, s3.x,s3.y,s3.z,s3.w};
            #pragma unroll
            for (int m = 0; m < 16; ++m) {
                xrA[m] += ex * cm[m];  xiA[m] -= ox * sm[m];
                xrB[m] += ey * cm[m];  xiB[m] -= oy * sm[m];
            }
        }
        char* xfb = lds + XF_OFF;
        const unsigned swzd = (unsigned)((nn & 7) << 4);
        #pragma unroll
        for (int m = 0; m < 16; ++m) {
            unsigned byte = ((unsigned)(m * 8192 + nn * 512 + i2 * 4)) ^ swzd;
            uint2 v2;
            v2.x = pack2(xrA[m], xiA[m]);
            v2.y = pack2(xrB[m], xiB[m]);
            *(uint2*)(xfb + byte) = v2;
        }
    }
    __syncthreads();

    // ---------- og pipeline (UNROLLED): einsum(k) || irfft(k-1), k = 0..8 ----
    char* xfb = lds + XF_OFF;
    float* outp = out + (size_t)(n0 + wid) * CC + col;
    const unsigned arow = (unsigned)(wid * 8192 + col * 512 + kq * 16);
    f32x4 sv0 = {0.f,0.f,0.f,0.f}, sv1 = {0.f,0.f,0.f,0.f};

    #pragma unroll
    for (int k = 0; k <= 8; ++k) {
        if (k < 8) {
            // einsum: OF[mode=wid], o-tile k, K=256 over (i,ri)
            char* ofb = lds + ((k & 1) ? OF1_OFF : OF0_OFF);
            const bf16x8* wog = wb + (size_t)((wid * 8 + k) * 2) * (8 * 64);
            f32x4 accR = {0.f, 0.f, 0.f, 0.f};
            f32x4 accI = {0.f, 0.f, 0.f, 0.f};
            #pragma unroll
            for (int ck = 0; ck < 8; ++ck) {
                bf16x8 af = *(const bf16x8*)(xfb + ((arow + (unsigned)(ck * 64)) ^ swza));
                bf16x8 bR = wog[(0 * 8 + ck) * 64 + lane];
                bf16x8 bI = wog[(1 * 8 + ck) * 64 + lane];
                accR = __builtin_amdgcn_mfma_f32_16x16x32_bf16(af, bR, accR, 0, 0, 0);
                accI = __builtin_amdgcn_mfma_f32_16x16x32_bf16(af, bI, accI, 0, 0, 0);
            }
            #pragma unroll
            for (int j = 0; j < 4; ++j) {
                unsigned no = (unsigned)((kq * 4 + j) * 16 + col);
                unsigned addr = no * 64u + (((unsigned)(wid * 4)) ^ ((no & 7) << 3));
                *(unsigned*)(ofb + addr) = pack2(accR[j], accI[j]);
            }
        }
        if (k > 0) {
            // irfft of o-tile (k-1); wave wid = n-row
            const int og = k - 1;
            char* ofb = lds + ((og & 1) ? OF1_OFF : OF0_OFF);
            unsigned rowb = (unsigned)((wid * 16 + col) * 64);
            bf16x4 lo = *(const bf16x4*)(ofb + rowb + (((unsigned)(kq * 16)) ^ swzo));
            bf16x4 hi = *(const bf16x4*)(ofb + rowb + (((unsigned)(kq * 16 + 8)) ^ swzo));
            bf16x8 pf;
            #pragma unroll
            for (int q = 0; q < 4; ++q) { pf[q] = lo[q]; pf[4 + q] = hi[q]; }
            f32x4 z = {0.f, 0.f, 0.f, 0.f};
            f32x4 c0 = __builtin_amdgcn_mfma_f32_16x16x32_bf16(dtf0, pf, z, 0, 0, 0);
            f32x4 c1 = __builtin_amdgcn_mfma_f32_16x16x32_bf16(dtf1, pf, z, 0, 0, 0);
            if ((og & 1) == 0) {
                sv0 = c0; sv1 = c1;           // buffer even og; store with odd og
            } else {
                float* opE = outp + (og - 1) * 16;
                float* opO = outp + og * 16;
                #pragma unroll
                for (int j = 0; j < 4; ++j) {
                    int t0 = kq * 4 + j;
                    __builtin_nontemporal_store(sv0[j], &opE[(size_t)t0 * NC]);
                    __builtin_nontemporal_store(c0[j],  &opO[(size_t)t0 * NC]);
                    __builtin_nontemporal_store(sv1[j], &opE[(size_t)(t0 + 16) * NC]);
                    __builtin_nontemporal_store(c1[j],  &opO[(size_t)(t0 + 16) * NC]);
                }
            }
        }
        __syncthreads();
    }
}

// ============================================================================
// Fallback (round-1 proven kernel) — used only if ws_size < 2 MB.
// ============================================================================
#define FBN 8
#define FXST 36
__global__ __launch_bounds__(512, 2)
void spectral_fused(const float* __restrict__ x,
                    const float* __restrict__ w,
                    float* __restrict__ out) {
    extern __shared__ float flds[];
    float* xf    = flds;
    float* ftabc = flds + FBN * CC * FXST;
    float* ftabs = ftabc + 512;

    const int tid = threadIdx.x;
    const int n0  = blockIdx.x * FBN;

    {
        const int m = tid >> 5;
        const int t = tid & 31;
        const float ang = 0.19634954084936207f * (float)((m * t) & 31);
        float s, c; sincosf(ang, &s, &c);
        ftabc[tid] = c; ftabs[tid] = s;
    }
    __syncthreads();
    {
        const int i   = tid & 127;
        const int nnA = tid >> 7;
        const int nnB = nnA + 4;
        float xra[MM], xia[MM], xrb[MM], xib[MM];
        #pragma unroll
        for (int m = 0; m < MM; ++m) { xra[m]=0.f; xia[m]=0.f; xrb[m]=0.f; xib[m]=0.f; }
        const float* xA = x + (size_t)(n0 + nnA) * CC + i;
        const float* xB = x + (size_t)(n0 + nnB) * CC + i;
        for (int t = 0; t < TT; ++t) {
            const float va = xA[(size_t)t * NC];
            const float vb = xB[(size_t)t * NC];
            #pragma unroll
            for (int m = 0; m < MM; ++m) {
                const float c = ftabc[(m << 5) + t];
                const float s = ftabs[(m << 5) + t];
                xra[m] += va * c;  xia[m] -= va * s;
                xrb[m] += vb * c;  xib[m] -= vb * s;
            }
        }
        float* dA = xf + (size_t)(nnA * CC + i) * FXST;
        float* dB = xf + (size_t)(nnB * CC + i) * FXST;
        #pragma unroll
        for (int j = 0; j < 8; ++j) {
            *(float4*)(dA + 4 * j) = make_float4(xra[2*j], xia[2*j], xra[2*j+1], xia[2*j+1]);
            *(float4*)(dB + 4 * j) = make_float4(xrb[2*j], xib[2*j], xrb[2*j+1], xib[2*j+1]);
        }
    }
    __syncthreads();
    const int o   = tid & 127;
    const int nnA = tid >> 7;
    const int nnB = nnA + 4;
    float ar[MM], ai_[MM], br[MM], bi_[MM];
    #pragma unroll
    for (int m = 0; m < MM; ++m) { ar[m]=0.f; ai_[m]=0.f; br[m]=0.f; bi_[m]=0.f; }
    const float* qa0 = xf + (size_t)(nnA * CC) * FXST;
    const float* qb0 = xf + (size_t)(nnB * CC) * FXST;
    float4 wv[8];
    {
        const float4* wp = (const float4*)(w + (size_t)o * 32);
        #pragma unroll
        for (int j = 0; j < 8; ++j) wv[j] = wp[j];
    }
    for (int i = 0; i < CC; ++i) {
        float4 xa4[8], xb4[8];
        const float4* qa = (const float4*)(qa0 + i * FXST);
        const float4* qb = (const float4*)(qb0 + i * FXST);
        #pragma unroll
        for (int j = 0; j < 8; ++j) { xa4[j] = qa[j]; xb4[j] = qb[j]; }
        float4 wn[8];
        if (i + 1 < CC) {
            const float4* wp = (const float4*)(w + (size_t)((i + 1) * CC + o) * 32);
            #pragma unroll
            for (int j = 0; j < 8; ++j) wn[j] = wp[j];
        }
        #pragma unroll
        for (int j = 0; j < 8; ++j) {
            const int m0 = 2 * j, m1 = 2 * j + 1;
            ar[m0]  += xa4[j].x * wv[j].x - xa4[j].y * wv[j].y;
            ai_[m0] += xa4[j].x * wv[j].y + xa4[j].y * wv[j].x;
            br[m0]  += xb4[j].x * wv[j].x - xb4[j].y * wv[j].y;
            bi_[m0] += xb4[j].x * wv[j].y + xb4[j].y * wv[j].x;
            ar[m1]  += xa4[j].z * wv[j].z - xa4[j].w * wv[j].w;
            ai_[m1] += xa4[j].z * wv[j].w + xa4[j].w * wv[j].z;
            br[m1]  += xb4[j].z * wv[j].z - xb4[j].w * wv[j].w;
            bi_[m1] += xb4[j].z * wv[j].w + xb4[j].w * wv[j].z;
        }
        #pragma unroll
        for (int j = 0; j < 8; ++j) wv[j] = wn[j];
    }
    {
        const float inv = 1.0f / 32.0f;
        const size_t obA = (size_t)(n0 + nnA) * CC + o;
        const size_t obB = (size_t)(n0 + nnB) * CC + o;
        for (int t = 0; t < TT; ++t) {
            float accA = 0.f, accB = 0.f;
            #pragma unroll
            for (int m = 1; m < MM; ++m) {
                const float c = ftabc[(m << 5) + t];
                const float s = ftabs[(m << 5) + t];
                accA += ar[m] * c - ai_[m] * s;
                accB += br[m] * c - bi_[m] * s;
            }
            out[(size_t)t * NC + obA] = (ar[0] + 2.f * accA) * inv;
            out[(size_t)t * NC + obB] = (br[0] + 2.f * accB) * inv;
        }
    }
}

extern "C" void kernel_launch(void* const* d_in, const int* in_sizes, int n_in,
                              void* d_out, int out_size, void* d_ws, size_t ws_size,
                              hipStream_t stream) {
    (void)in_sizes; (void)n_in; (void)out_size;
    const float* x = (const float*)d_in[0];
    const float* w = (const float*)d_in[1];
    float* out     = (float*)d_out;

    if (d_ws != nullptr && ws_size >= (size_t)2 * 1024 * 1024) {
        bf16x8* wbuf = (bf16x8*)d_ws;
        hipLaunchKernelGGL(repack_w, dim3(512), dim3(256), 0, stream, w, wbuf);
        hipLaunchKernelGGL(spectral_mfma, dim3(NPT / BN), dim3(1024), LDS_BYTES, stream,
                           x, wbuf, out);
    } else {
        const size_t lds_bytes = (size_t)(FBN * CC * FXST + 1024) * sizeof(float);
        hipLaunchKernelGGL(spectral_fused, dim3(NPT / FBN), dim3(512), lds_bytes, stream,
                           x, w, out);
    }
}

// Round 16
// 435.408 us; speedup vs baseline: 5.0732x; 1.0069x over previous
//
#include <hip/hip_runtime.h>
#include <math.h>

typedef short bf16x8 __attribute__((ext_vector_type(8)));
typedef short bf16x4 __attribute__((ext_vector_type(4)));
typedef float f32x4  __attribute__((ext_vector_type(4)));
typedef float f32x2  __attribute__((ext_vector_type(2)));   // clang-native for NT builtins

#define TT 32
#define MM 16
#define CC 128
#define NPT 32768
#define NC 4194304          // NPT*CC, elements per time-slice
#define BN 16               // n-points per block

// ---- LDS layout (bytes), total 163840 = 160 KiB exactly ----
// XF : bf16 [m16][n16][i128][ri2] = 131072 B, phys = L ^ ((n&7)<<4)
// OF0/OF1 : bf16 [no256][k2_32], row stride 64 B, byte-in-row b -> b ^ ((no&7)<<3)
// rfft tables (f32[512] x2 = 4 KB) OVERLAY OF1[0:4096] (dead until og k=1)
#define XF_OFF   0
#define OF0_OFF  131072
#define OF1_OFF  147456
#define LDS_BYTES 163840

static __device__ __forceinline__ unsigned short f2bf(float f) {
    union { float f; unsigned u; } v; v.f = f;
    unsigned r = v.u + 0x7FFFu + ((v.u >> 16) & 1u);   // RNE
    return (unsigned short)(r >> 16);
}
static __device__ __forceinline__ unsigned pack2(float lo, float hi) {
    return (unsigned)f2bf(lo) | ((unsigned)f2bf(hi) << 16);
}

// ============================================================================
// Weight repack: w[i][o][m][ri] f32 -> bf16 MFMA B-fragments in d_ws.
// Layout (short8 rows): WB[m][og][riOut][ck][lane] — per (m,og) contiguous 16 KB.
// Row holds B[k = ck*32 + (lane>>4)*8 + j][o = og*16 + (lane&15)], j=0..7,
// k = 2i+ri_in stacking:  B_R = {+Wr, -Wi},  B_I = {+Wi, +Wr}.
// ============================================================================
__global__ void repack_w(const float* __restrict__ w, bf16x8* __restrict__ wb) {
    int r = blockIdx.x * blockDim.x + threadIdx.x;    // 0..131071
    int lane = r & 63;
    int r2 = r >> 6;
    int ck = r2 & 7;
    int r3 = r2 >> 3;
    int ri = r3 & 1;
    int r4 = r3 >> 1;
    int og = r4 & 7;
    int m  = r4 >> 3;
    int o = og * 16 + (lane & 15);
    int kbase = ck * 32 + (lane >> 4) * 8;
    bf16x8 v;
    #pragma unroll
    for (int j = 0; j < 8; ++j) {
        int k = kbase + j;
        int i = k >> 1, ko = k & 1;
        const float* wp = w + ((size_t)(i * 128 + o) * 16 + m) * 2;
        float val;
        if (ri == 0) val = ko ? -wp[1] : wp[0];
        else         val = ko ?  wp[0] : wp[1];
        v[j] = (short)f2bf(val);
    }
    wb[r] = v;
}

// ============================================================================
// Main fused kernel: 2048 blocks x 1024 threads (16 waves), BN=16.
// R15 structure (NT x loads / NT out stores, unrolled og ping-pong pipeline)
// + dtf table reads as float4 (conflict-free; R15's scalar reads were 8-way).
// ============================================================================
__global__ __launch_bounds__(1024, 2)
void spectral_mfma(const float* __restrict__ x, const bf16x8* __restrict__ wb,
                   float* __restrict__ out) {
    extern __shared__ char lds[];
    float* tabc = (float*)(lds + OF1_OFF);          // overlays OF1[0:2048]
    float* tabs = (float*)(lds + OF1_OFF + 2048);   // overlays OF1[2048:4096]
    const int tid = threadIdx.x;
    const int n0  = blockIdx.x * BN;

    // einsum/irfft mapping
    const int lane = tid & 63;
    const int wid  = tid >> 6;          // einsum: mode; irfft: n-row
    const int col  = lane & 15;
    const int kq   = lane >> 4;
    const unsigned swza = (unsigned)((col & 7) << 4);   // XF read swizzle
    const unsigned swzo = (unsigned)((col & 7) << 3);   // OF swizzle (no&7==col&7)

    // ---------- phase 0: rfft tables [t][m] (overlay OF1) ----------
    if (tid < 512) {
        int m = tid & 15, t = tid >> 4;
        float s, c;
        sincosf(0.19634954084936207f * (float)((m * t) & 31), &s, &c);
        tabc[t * 16 + m] = c;
        tabs[t * 16 + m] = s;
    }
    __syncthreads();

    // per-thread irfft fragments DT[t=col | col+16][k2 = kq*8 + jj],
    // from tables via conflict-free float4 reads (m-range kq*4..kq*4+3 contiguous)
    bf16x8 dtf0, dtf1;
    {
        float4 c0 = *(const float4*)&tabc[col * 16 + kq * 4];
        float4 s0 = *(const float4*)&tabs[col * 16 + kq * 4];
        float4 c1 = *(const float4*)&tabc[(col + 16) * 16 + kq * 4];
        float4 s1 = *(const float4*)&tabs[(col + 16) * 16 + kq * 4];
        float cm0[4] = {c0.x, c0.y, c0.z, c0.w};
        float sm0[4] = {s0.x, s0.y, s0.z, s0.w};
        float cm1[4] = {c1.x, c1.y, c1.z, c1.w};
        float sm1[4] = {s1.x, s1.y, s1.z, s1.w};
        #pragma unroll
        for (int jm = 0; jm < 4; ++jm) {
            int m = kq * 4 + jm;
            float alpha = (m == 0) ? 0.03125f : 0.0625f;   // 1/32, 2/32
            dtf0[jm * 2 + 0] = (short)f2bf(alpha * cm0[jm]);
            dtf0[jm * 2 + 1] = (m == 0) ? (short)0 : (short)f2bf(-alpha * sm0[jm]);
            dtf1[jm * 2 + 0] = (short)f2bf(alpha * cm1[jm]);
            dtf1[jm * 2 + 1] = (m == 0) ? (short)0 : (short)f2bf(-alpha * sm1[jm]);
        }
    }

    // ---------- phase 1: folded rfft, two adjacent i-columns per thread ----------
    {
        const int nn = tid >> 6;            // 0..15
        const int i2 = (tid & 63) * 2;
        const float* xp = x + (size_t)(n0 + nn) * CC + i2;
        f32x2 x0  = __builtin_nontemporal_load((const f32x2*)(xp));
        f32x2 x16 = __builtin_nontemporal_load((const f32x2*)(xp + (size_t)16 * NC));
        float xrA[16], xiA[16], xrB[16], xiB[16];
        #pragma unroll
        for (int m = 0; m < 16; ++m) {
            float sgn = (m & 1) ? -1.f : 1.f;
            xrA[m] = x0[0] + sgn * x16[0];
            xrB[m] = x0[1] + sgn * x16[1];
            xiA[m] = 0.f; xiB[m] = 0.f;
        }
        #pragma unroll 3
        for (int t = 1; t <= 15; ++t) {
            f32x2 a = __builtin_nontemporal_load((const f32x2*)(xp + (size_t)t * NC));
            f32x2 b = __builtin_nontemporal_load((const f32x2*)(xp + (size_t)(32 - t) * NC));
            float ex = a[0] + b[0], ey = a[1] + b[1];
            float ox = a[0] - b[0], oy = a[1] - b[1];
            float4 c0 = *(const float4*)&tabc[t * 16 + 0];
            float4 c1 = *(const float4*)&tabc[t * 16 + 4];
            float4 c2 = *(const float4*)&tabc[t * 16 + 8];
            float4 c3 = *(const float4*)&tabc[t * 16 + 12];
            float4 s0 = *(const float4*)&tabs[t * 16 + 0];
            float4 s1 = *(const float4*)&tabs[t * 16 + 4];
            float4 s2 = *(const float4*)&tabs[t * 16 + 8];
            float4 s3 = *(const float4*)&tabs[t * 16 + 12];
            float cm[16] = {c0.x,c0.y,c0.z,c0.w, c1.x,c1.y,c1.z,c1.w,
                            c2.x,c2.y,c2.z,c2.w, c3.x,c3.y,c3.z,c3.w};
            float sm[16] = {s0.x,s0.y,s0.z,s0.w, s1.x,s1.y,s1.z,s1.w,
                            s2.x,s2.y,s2.z,s2.w, s3.x,s3.y,s3.z,s3.w};
            #pragma unroll
            for (int m = 0; m < 16; ++m) {
                xrA[m] += ex * cm[m];  xiA[m] -= ox * sm[m];
                xrB[m] += ey * cm[m];  xiB[m] -= oy * sm[m];
            }
        }
        char* xfb = lds + XF_OFF;
        const unsigned swzd = (unsigned)((nn & 7) << 4);
        #pragma unroll
        for (int m = 0; m < 16; ++m) {
            unsigned byte = ((unsigned)(m * 8192 + nn * 512 + i2 * 4)) ^ swzd;
            uint2 v2;
            v2.x = pack2(xrA[m], xiA[m]);
            v2.y = pack2(xrB[m], xiB[m]);
            *(uint2*)(xfb + byte) = v2;
        }
    }
    __syncthreads();

    // ---------- og pipeline (UNROLLED): einsum(k) || irfft(k-1), k = 0..8 ----
    char* xfb = lds + XF_OFF;
    float* outp = out + (size_t)(n0 + wid) * CC + col;
    const unsigned arow = (unsigned)(wid * 8192 + col * 512 + kq * 16);
    f32x4 sv0 = {0.f,0.f,0.f,0.f}, sv1 = {0.f,0.f,0.f,0.f};

    #pragma unroll
    for (int k = 0; k <= 8; ++k) {
        if (k < 8) {
            // einsum: OF[mode=wid], o-tile k, K=256 over (i,ri)
            char* ofb = lds + ((k & 1) ? OF1_OFF : OF0_OFF);
            const bf16x8* wog = wb + (size_t)((wid * 8 + k) * 2) * (8 * 64);
            f32x4 accR = {0.f, 0.f, 0.f, 0.f};
            f32x4 accI = {0.f, 0.f, 0.f, 0.f};
            #pragma unroll
            for (int ck = 0; ck < 8; ++ck) {
                bf16x8 af = *(const bf16x8*)(xfb + ((arow + (unsigned)(ck * 64)) ^ swza));
                bf16x8 bR = wog[(0 * 8 + ck) * 64 + lane];
                bf16x8 bI = wog[(1 * 8 + ck) * 64 + lane];
                accR = __builtin_amdgcn_mfma_f32_16x16x32_bf16(af, bR, accR, 0, 0, 0);
                accI = __builtin_amdgcn_mfma_f32_16x16x32_bf16(af, bI, accI, 0, 0, 0);
            }
            #pragma unroll
            for (int j = 0; j < 4; ++j) {
                unsigned no = (unsigned)((kq * 4 + j) * 16 + col);
                unsigned addr = no * 64u + (((unsigned)(wid * 4)) ^ ((no & 7) << 3));
                *(unsigned*)(ofb + addr) = pack2(accR[j], accI[j]);
            }
        }
        if (k > 0) {
            // irfft of o-tile (k-1); wave wid = n-row
            const int og = k - 1;
            char* ofb = lds + ((og & 1) ? OF1_OFF : OF0_OFF);
            unsigned rowb = (unsigned)((wid * 16 + col) * 64);
            bf16x4 lo = *(const bf16x4*)(ofb + rowb + (((unsigned)(kq * 16)) ^ swzo));
            bf16x4 hi = *(const bf16x4*)(ofb + rowb + (((unsigned)(kq * 16 + 8)) ^ swzo));
            bf16x8 pf;
            #pragma unroll
            for (int q = 0; q < 4; ++q) { pf[q] = lo[q]; pf[4 + q] = hi[q]; }
            f32x4 z = {0.f, 0.f, 0.f, 0.f};
            f32x4 c0 = __builtin_amdgcn_mfma_f32_16x16x32_bf16(dtf0, pf, z, 0, 0, 0);
            f32x4 c1 = __builtin_amdgcn_mfma_f32_16x16x32_bf16(dtf1, pf, z, 0, 0, 0);
            if ((og & 1) == 0) {
                sv0 = c0; sv1 = c1;           // buffer even og; store with odd og
            } else {
                float* opE = outp + (og - 1) * 16;
                float* opO = outp + og * 16;
                #pragma unroll
                for (int j = 0; j < 4; ++j) {
                    int t0 = kq * 4 + j;
                    __builtin_nontemporal_store(sv0[j], &opE[(size_t)t0 * NC]);
                    __builtin_nontemporal_store(c0[j],  &opO[(size_t)t0 * NC]);
                    __builtin_nontemporal_store(sv1[j], &opE[(size_t)(t0 + 16) * NC]);
                    __builtin_nontemporal_store(c1[j],  &opO[(size_t)(t0 + 16) * NC]);
                }
            }
        }
        __syncthreads();
    }
}

// ============================================================================
// Fallback (round-1 proven kernel) — used only if ws_size < 2 MB.
// ============================================================================
#define FBN 8
#define FXST 36
__global__ __launch_bounds__(512, 2)
void spectral_fused(const float* __restrict__ x,
                    const float* __restrict__ w,
                    float* __restrict__ out) {
    extern __shared__ float flds[];
    float* xf    = flds;
    float* ftabc = flds + FBN * CC * FXST;
    float* ftabs = ftabc + 512;

    const int tid = threadIdx.x;
    const int n0  = blockIdx.x * FBN;

    {
        const int m = tid >> 5;
        const int t = tid & 31;
        const float ang = 0.19634954084936207f * (float)((m * t) & 31);
        float s, c; sincosf(ang, &s, &c);
        ftabc[tid] = c; ftabs[tid] = s;
    }
    __syncthreads();
    {
        const int i   = tid & 127;
        const int nnA = tid >> 7;
        const int nnB = nnA + 4;
        float xra[MM], xia[MM], xrb[MM], xib[MM];
        #pragma unroll
        for (int m = 0; m < MM; ++m) { xra[m]=0.f; xia[m]=0.f; xrb[m]=0.f; xib[m]=0.f; }
        const float* xA = x + (size_t)(n0 + nnA) * CC + i;
        const float* xB = x + (size_t)(n0 + nnB) * CC + i;
        for (int t = 0; t < TT; ++t) {
            const float va = xA[(size_t)t * NC];
            const float vb = xB[(size_t)t * NC];
            #pragma unroll
            for (int m = 0; m < MM; ++m) {
                const float c = ftabc[(m << 5) + t];
                const float s = ftabs[(m << 5) + t];
                xra[m] += va * c;  xia[m] -= va * s;
                xrb[m] += vb * c;  xib[m] -= vb * s;
            }
        }
        float* dA = xf + (size_t)(nnA * CC + i) * FXST;
        float* dB = xf + (size_t)(nnB * CC + i) * FXST;
        #pragma unroll
        for (int j = 0; j < 8; ++j) {
            *(float4*)(dA + 4 * j) = make_float4(xra[2*j], xia[2*j], xra[2*j+1], xia[2*j+1]);
            *(float4*)(dB + 4 * j) = make_float4(xrb[2*j], xib[2*j], xrb[2*j+1], xib[2*j+1]);
        }
    }
    __syncthreads();
    const int o   = tid & 127;
    const int nnA = tid >> 7;
    const int nnB = nnA + 4;
    float ar[MM], ai_[MM], br[MM], bi_[MM];
    #pragma unroll
    for (int m = 0; m < MM; ++m) { ar[m]=0.f; ai_[m]=0.f; br[m]=0.f; bi_[m]=0.f; }
    const float* qa0 = xf + (size_t)(nnA * CC) * FXST;
    const float* qb0 = xf + (size_t)(nnB * CC) * FXST;
    float4 wv[8];
    {
        const float4* wp = (const float4*)(w + (size_t)o * 32);
        #pragma unroll
        for (int j = 0; j < 8; ++j) wv[j] = wp[j];
    }
    for (int i = 0; i < CC; ++i) {
        float4 xa4[8], xb4[8];
        const float4* qa = (const float4*)(qa0 + i * FXST);
        const float4* qb = (const float4*)(qb0 + i * FXST);
        #pragma unroll
        for (int j = 0; j < 8; ++j) { xa4[j] = qa[j]; xb4[j] = qb[j]; }
        float4 wn[8];
        if (i + 1 < CC) {
            const float4* wp = (const float4*)(w + (size_t)((i + 1) * CC + o) * 32);
            #pragma unroll
            for (int j = 0; j < 8; ++j) wn[j] = wp[j];
        }
        #pragma unroll
        for (int j = 0; j < 8; ++j) {
            const int m0 = 2 * j, m1 = 2 * j + 1;
            ar[m0]  += xa4[j].x * wv[j].x - xa4[j].y * wv[j].y;
            ai_[m0] += xa4[j].x * wv[j].y + xa4[j].y * wv[j].x;
            br[m0]  += xb4[j].x * wv[j].x - xb4[j].y * wv[j].y;
            bi_[m0] += xb4[j].x * wv[j].y + xb4[j].y * wv[j].x;
            ar[m1]  += xa4[j].z * wv[j].z - xa4[j].w * wv[j].w;
            ai_[m1] += xa4[j].z * wv[j].w + xa4[j].w * wv[j].z;
            br[m1]  += xb4[j].z * wv[j].z - xb4[j].w * wv[j].w;
            bi_[m1] += xb4[j].z * wv[j].w + xb4[j].w * wv[j].z;
        }
        #pragma unroll
        for (int j = 0; j < 8; ++j) wv[j] = wn[j];
    }
    {
        const float inv = 1.0f / 32.0f;
        const size_t obA = (size_t)(n0 + nnA) * CC + o;
        const size_t obB = (size_t)(n0 + nnB) * CC + o;
        for (int t = 0; t < TT; ++t) {
            float accA = 0.f, accB = 0.f;
            #pragma unroll
            for (int m = 1; m < MM; ++m) {
                const float c = ftabc[(m << 5) + t];
                const float s = ftabs[(m << 5) + t];
                accA += ar[m] * c - ai_[m] * s;
                accB += br[m] * c - bi_[m] * s;
            }
            out[(size_t)t * NC + obA] = (ar[0] + 2.f * accA) * inv;
            out[(size_t)t * NC + obB] = (br[0] + 2.f * accB) * inv;
        }
    }
}

extern "C" void kernel_launch(void* const* d_in, const int* in_sizes, int n_in,
                              void* d_out, int out_size, void* d_ws, size_t ws_size,
                              hipStream_t stream) {
    (void)in_sizes; (void)n_in; (void)out_size;
    const float* x = (const float*)d_in[0];
    const float* w = (const float*)d_in[1];
    float* out     = (float*)d_out;

    if (d_ws != nullptr && ws_size >= (size_t)2 * 1024 * 1024) {
        bf16x8* wbuf = (bf16x8*)d_ws;
        hipLaunchKernelGGL(repack_w, dim3(512), dim3(256), 0, stream, w, wbuf);
        hipLaunchKernelGGL(spectral_mfma, dim3(NPT / BN), dim3(1024), LDS_BYTES, stream,
                           x, wbuf, out);
    } else {
        const size_t lds_bytes = (size_t)(FBN * CC * FXST + 1024) * sizeof(float);
        hipLaunchKernelGGL(spectral_fused, dim3(NPT / FBN), dim3(512), lds_bytes, stream,
                           x, w, out);
    }
}